// Round 7
// baseline (407.157 us; speedup 1.0000x reference)
//
#include <hip/hip_runtime.h>
#include <hip/hip_bf16.h>

#define B_ROWS 256
#define S_SUP  65536
#define D_DIM  768
#define QSZ    512
#define NPH    4            // K phases
#define BKP    192          // k per phase
#define NS     6            // sub-steps per phase (SK=32)
#define SK     32
#define APH    98304        // A per phase: 24 planes * 4096 B = 96 KB
#define BUF0   98304
#define BUF1   114688

typedef short bf16x8 __attribute__((ext_vector_type(8)));
typedef float f32x4  __attribute__((ext_vector_type(4)));
typedef float f32x16 __attribute__((ext_vector_type(16)));

__device__ __forceinline__ bf16x8 cvt8(float4 a, float4 b) {
  bf16x8 r;
  r[0] = (short)(__float_as_uint(a.x) >> 16);
  r[1] = (short)(__float_as_uint(a.y) >> 16);
  r[2] = (short)(__float_as_uint(a.z) >> 16);
  r[3] = (short)(__float_as_uint(a.w) >> 16);
  r[4] = (short)(__float_as_uint(b.x) >> 16);
  r[5] = (short)(__float_as_uint(b.y) >> 16);
  r[6] = (short)(__float_as_uint(b.z) >> 16);
  r[7] = (short)(__float_as_uint(b.w) >> 16);
  return r;
}

__device__ __forceinline__ void gl_lds16(const void* g, void* l) {
  __builtin_amdgcn_global_load_lds(
      (const __attribute__((address_space(1))) unsigned int*)g,
      (__attribute__((address_space(3))) unsigned int*)l, 16, 0, 0);
}

// block-wide sum (float), result broadcast to all 256 threads (4 waves)
__device__ __forceinline__ float block_sum(float v) {
  __shared__ float tmp[4];
  #pragma unroll
  for (int m = 32; m >= 1; m >>= 1) v += __shfl_xor(v, m, 64);
  __syncthreads();
  if ((threadIdx.x & 63) == 0) tmp[threadIdx.x >> 6] = v;
  __syncthreads();
  return tmp[0] + tmp[1] + tmp[2] + tmp[3];
}

__device__ __forceinline__ double block_sum_d(double v) {
  __shared__ double tmp[4];
  #pragma unroll
  for (int m = 32; m >= 1; m >>= 1) v += __shfl_xor(v, m, 64);
  __syncthreads();
  if ((threadIdx.x & 63) == 0) tmp[threadIdx.x >> 6] = v;
  __syncthreads();
  return tmp[0] + tmp[1] + tmp[2] + tmp[3];
}

// ---- kernel 0: zero accumulators ----
__global__ __launch_bounds__(256) void init_kernel(unsigned long long* gmax, double* bden) {
  int t = threadIdx.x;
  gmax[t] = 0ull;
  for (int i = t; i < 3 * B_ROWS; i += 256) bden[i] = 0.0;
}

// ---- kernel 1: augs[j-1] = normalize(V[j]*L); j==0 -> org_bf16 image ----
// A image: plane-major LINEAR in k: plane gk = k>>3 (0..95), 4096 B each:
// ushort idx = gk*2048 + r*8 + e.  (LDS copy per phase is planes [24p, 24p+24).)
__global__ __launch_bounds__(256) void prep_kernel(const float* __restrict__ V,
                                                   const float* __restrict__ L,
                                                   unsigned short* __restrict__ orgb,
                                                   float* __restrict__ augs) {
  int jb = blockIdx.x;            // 0..1023
  int j = jb >> 8, b = jb & 255;
  int tid = threadIdx.x;
  __shared__ float srow[D_DIM];
  const float* v = V + ((size_t)j * B_ROWS + b) * D_DIM;
  const float* l = L + (size_t)b * D_DIM;
  float p[3]; float ssq = 0.f;
  #pragma unroll
  for (int i = 0; i < 3; ++i) {
    int k = tid + 256 * i;
    p[i] = v[k] * l[k];
    ssq += p[i] * p[i];
  }
  ssq = block_sum(ssq);
  float inv = 1.0f / fmaxf(sqrtf(ssq), 1e-12f);
  if (j == 0) {
    #pragma unroll
    for (int i = 0; i < 3; ++i) srow[tid + 256 * i] = p[i] * inv;
    __syncthreads();
    if (tid < 96) {                       // plane gk = tid, k0 = 8*tid
      int k0 = tid * 8;
      float4 f0 = *(const float4*)&srow[k0];
      float4 f1 = *(const float4*)&srow[k0 + 4];
      bf16x8 hv = cvt8(f0, f1);
      *(bf16x8*)(orgb + tid * 2048 + b * 8) = hv;
    }
  } else {
    float* dst = augs + ((size_t)(j - 1) * B_ROWS + b) * D_DIM;
    #pragma unroll
    for (int i = 0; i < 3; ++i) dst[tid + 256 * i] = p[i] * inv;
  }
}

// ---- kernel 2: sim = org @ sf^T (bf16 MFMA 32x32x16), per-row argmax ----
// Port-traffic-minimal design: grid 256 (1 block/CU), BN=256 -> A image fetched
// ONCE per CU (384 KB) + B once (768 KB) = 1.13 MB/CU ~ 48 us port floor.
// 4 K-phases (BK=192, A 96 KB LDS via gl_lds). B: 2-deep static reg staging
// (sets P/Q) + double-buffered 16 KB LDS; sub-step barriers are raw s_barrier +
// lgkmcnt(0) ONLY (no vmcnt drain -> loads stay in flight across barriers).
__global__ __launch_bounds__(512, 2) void sim_argmax_kernel(const unsigned short* __restrict__ orgb,
                                                            const float* __restrict__ sf,
                                                            unsigned long long* __restrict__ gmax) {
  const int tid = threadIdx.x;
  const int w   = tid >> 6;           // wave 0..7
  const int l   = tid & 63;
  const int h   = l >> 5;             // half 0/1 (k-slice select)
  const int c31 = l & 31;
  const int wr  = w & 1;              // row band (128 rows)
  const int wc  = w >> 1;             // col band 0..3 (64 cols)
  const int s0  = blockIdx.x * 256;

  __shared__ __align__(16) char smem[131072];   // A 96K | buf0 16K | buf1 16K

  f32x16 acc[8];                      // rt*2+nt, rt 0..3, nt 0..1 (static idx only)
  #pragma unroll
  for (int t = 0; t < 8; ++t)
    #pragma unroll
    for (int r = 0; r < 16; ++r) acc[t][r] = 0.f;

  // B staging: thread -> col bc_st = tid>>1, 16-k half kh = tid&1; 64 B contiguous
  const int bc_st = tid >> 1;
  const int kh    = tid & 1;
  const float* bsrc = sf + (size_t)(s0 + bc_st) * D_DIM + kh * 16;
  const int pl0 = kh * 2, pl1 = kh * 2 + 1;
  const int wslot0 = ((bc_st ^ pl0) & 255) * 16;
  const int wslot1 = ((bc_st ^ pl1) & 255) * 16;

  // A staging: 12 x gl_lds16 per phase, verbatim linear copy
  const char* agb = (const char*)orgb + tid * 16;
  char* adst = smem + tid * 16;

  // read-side constants
  const int row_off = (wr * 128 + c31) * 16;     // + rt*512
  const int bc0 = wc * 64 + c31;
  const int bc1 = bc0 + 32;

  float4 p0, p1, p2, p3, q0, q1, q2, q3;

#define LOADP(ph, s) do { const float4* gp = (const float4*)(bsrc + (ph) * BKP + (s) * SK); \
    p0 = gp[0]; p1 = gp[1]; p2 = gp[2]; p3 = gp[3]; } while (0)
#define LOADQ(ph, s) do { const float4* gp = (const float4*)(bsrc + (ph) * BKP + (s) * SK); \
    q0 = gp[0]; q1 = gp[1]; q2 = gp[2]; q3 = gp[3]; } while (0)
#define WRITEP(buf) do { *(bf16x8*)((buf) + pl0 * 4096 + wslot0) = cvt8(p0, p1); \
    *(bf16x8*)((buf) + pl1 * 4096 + wslot1) = cvt8(p2, p3); } while (0)
#define WRITEQ(buf) do { *(bf16x8*)((buf) + pl0 * 4096 + wslot0) = cvt8(q0, q1); \
    *(bf16x8*)((buf) + pl1 * 4096 + wslot1) = cvt8(q2, q3); } while (0)
#define BAR() do { asm volatile("s_waitcnt lgkmcnt(0)" ::: "memory"); \
    __builtin_amdgcn_s_barrier(); __builtin_amdgcn_sched_barrier(0); } while (0)
#define COMPUTE(si, buf) do { \
    _Pragma("unroll") \
    for (int g01 = 0; g01 < 2; ++g01) { \
      const char* ap = smem + ((si) * 4 + g01 * 2 + h) * 4096 + row_off; \
      bf16x8 a0 = *(const bf16x8*)(ap); \
      bf16x8 a1 = *(const bf16x8*)(ap + 512); \
      bf16x8 a2 = *(const bf16x8*)(ap + 1024); \
      bf16x8 a3 = *(const bf16x8*)(ap + 1536); \
      const int bpl = g01 * 2 + h; \
      bf16x8 b0 = *(const bf16x8*)((buf) + bpl * 4096 + ((bc0 ^ bpl) & 255) * 16); \
      bf16x8 b1 = *(const bf16x8*)((buf) + bpl * 4096 + ((bc1 ^ bpl) & 255) * 16); \
      acc[0] = __builtin_amdgcn_mfma_f32_32x32x16_bf16(a0, b0, acc[0], 0, 0, 0); \
      acc[1] = __builtin_amdgcn_mfma_f32_32x32x16_bf16(a0, b1, acc[1], 0, 0, 0); \
      acc[2] = __builtin_amdgcn_mfma_f32_32x32x16_bf16(a1, b0, acc[2], 0, 0, 0); \
      acc[3] = __builtin_amdgcn_mfma_f32_32x32x16_bf16(a1, b1, acc[3], 0, 0, 0); \
      acc[4] = __builtin_amdgcn_mfma_f32_32x32x16_bf16(a2, b0, acc[4], 0, 0, 0); \
      acc[5] = __builtin_amdgcn_mfma_f32_32x32x16_bf16(a2, b1, acc[5], 0, 0, 0); \
      acc[6] = __builtin_amdgcn_mfma_f32_32x32x16_bf16(a3, b0, acc[6], 0, 0, 0); \
      acc[7] = __builtin_amdgcn_mfma_f32_32x32x16_bf16(a3, b1, acc[7], 0, 0, 0); \
    } } while (0)

  char* const b0p = smem + BUF0;
  char* const b1p = smem + BUF1;

  for (int ph = 0; ph < NPH; ++ph) {
    // ---- phase prologue: stage A (96 KB), prefetch B subs 0,1 ----
    {
      const char* g = agb + ph * APH;
      #pragma unroll
      for (int i = 0; i < 12; ++i) gl_lds16(g + i * 8192, adst + i * 8192);
    }
    LOADP(ph, 0);
    LOADQ(ph, 1);
    asm volatile("s_waitcnt vmcnt(8)" ::: "memory");   // A's 12 gl_lds done (P,Q remain)
    __builtin_amdgcn_s_barrier();                      // A visible to all
    __builtin_amdgcn_sched_barrier(0);
    WRITEP(b0p);                                       // sub 0 -> buf0 (waits P only)
    BAR();

    // ---- 6 sub-steps, fully unrolled: compute(si) || stage(si+1) || load(si+2) ----
    #pragma unroll
    for (int si = 0; si < NS; ++si) {
      char* bufc = (si & 1) ? b1p : b0p;
      char* bufn = (si & 1) ? b0p : b1p;
      COMPUTE(si, bufc);
      if (si < NS - 1) {
        if (si & 1) WRITEP(bufn); else WRITEQ(bufn);   // stage si+1
        if (si + 2 < NS) { if (si & 1) LOADQ(ph, si + 2); else LOADP(ph, si + 2); }
      }
      BAR();
    }
  }

#undef LOADP
#undef LOADQ
#undef WRITEP
#undef WRITEQ
#undef BAR
#undef COMPUTE

  // ---- epilogue: per-row argmax over the block's 256 cols ----
  float* smax = (float*)smem;            // [4 wc][256 rows]
  int*   sidx = (int*)(smem + 4096);
  #pragma unroll
  for (int rt = 0; rt < 4; ++rt) {
    #pragma unroll
    for (int rg = 0; rg < 16; ++rg) {
      float v0 = acc[rt * 2 + 0][rg];
      float v1 = acc[rt * 2 + 1][rg];
      int i0 = s0 + bc0;
      int i1 = s0 + bc1;
      float v; int idx;
      if (v1 > v0) { v = v1; idx = i1; } else { v = v0; idx = i0; }
      #pragma unroll
      for (int m = 1; m < 32; m <<= 1) {   // reduce 32 col-lanes (stays within half)
        float ov = __shfl_xor(v, m, 64);
        int   oi = __shfl_xor(idx, m, 64);
        if (ov > v || (ov == v && oi < idx)) { v = ov; idx = oi; }
      }
      if (c31 == 0) {
        int row = wr * 128 + rt * 32 + (rg & 3) + 8 * (rg >> 2) + 4 * h;  // m74/m101
        smax[wc * 256 + row] = v;
        sidx[wc * 256 + row] = idx;
      }
    }
  }
  __syncthreads();
  if (tid < 256) {
    int b = tid;
    float v  = smax[b];  int idx = sidx[b];
    #pragma unroll
    for (int w2 = 1; w2 < 4; ++w2) {
      float ov = smax[w2 * 256 + b]; int oi = sidx[w2 * 256 + b];
      if (ov > v || (ov == v && oi < idx)) { v = ov; idx = oi; }
    }
    unsigned u = __float_as_uint(v);
    unsigned key = (u & 0x80000000u) ? ~u : (u | 0x80000000u);
    unsigned long long packed = ((unsigned long long)key << 32) |
                                (unsigned long long)(0xFFFFFFFFu - (unsigned)idx);
    if (packed > gmax[b]) atomicMax(gmax + b, packed);   // stale read safe
  }
}

// ---- kernel 3: nn = normalize(sf[nn_idx]); nnT; num = dot(nn, augs[0][b]) / T ----
__global__ __launch_bounds__(256) void nn_kernel(const unsigned long long* __restrict__ gmax,
                                                 const float* __restrict__ sf,
                                                 const float* __restrict__ augs,
                                                 float* __restrict__ nn,
                                                 float* __restrict__ nnT,
                                                 float* __restrict__ num) {
  int b = blockIdx.x, tid = threadIdx.x;
  int idx = (int)(0xFFFFFFFFu - (unsigned)(gmax[b] & 0xFFFFFFFFull));
  const float* row = sf + (size_t)idx * D_DIM;
  float p[3]; float ssq = 0.f;
  #pragma unroll
  for (int i = 0; i < 3; ++i) { p[i] = row[tid + 256 * i]; ssq += p[i] * p[i]; }
  ssq = block_sum(ssq);
  float inv = 1.0f / fmaxf(sqrtf(ssq), 1e-12f);
  const float* a0 = augs + (size_t)b * D_DIM;    // augs[0][b]
  float dot = 0.f;
  #pragma unroll
  for (int i = 0; i < 3; ++i) {
    int k = tid + 256 * i;
    float nv = p[i] * inv;
    nn[(size_t)b * D_DIM + k] = nv;
    nnT[(size_t)k * B_ROWS + b] = nv;
    dot += nv * a0[k];
  }
  dot = block_sum(dot);
  if (tid == 0) num[b] = dot * 10.0f;            // 1/TEMP = 10
}

// ---- kernel 4: batch_den[j][b] += sum_i exp(10*dot(nn_b, aug_ji)) (double acc) ----
__global__ __launch_bounds__(256) void bden_kernel(const float* __restrict__ augs,
                                                   const float* __restrict__ nnT,
                                                   double* __restrict__ bden) {
  int jc = blockIdx.x;                 // 0..191
  int j = jc >> 6, c = jc & 63;
  int i0 = c * 4;
  __shared__ float s_aug[4 * D_DIM];
  const float* src = augs + ((size_t)j * B_ROWS + i0) * D_DIM;
  for (int idx = threadIdx.x; idx < 4 * D_DIM; idx += 256) s_aug[idx] = src[idx];
  __syncthreads();
  int b = threadIdx.x;
  float a0 = 0.f, a1 = 0.f, a2 = 0.f, a3 = 0.f;
  for (int k = 0; k < D_DIM; ++k) {
    float nv = nnT[(size_t)k * B_ROWS + b];
    a0 += nv * s_aug[k];
    a1 += nv * s_aug[D_DIM + k];
    a2 += nv * s_aug[2 * D_DIM + k];
    a3 += nv * s_aug[3 * D_DIM + k];
  }
  double v = exp((double)a0 * 10.0) + exp((double)a1 * 10.0) +
             exp((double)a2 * 10.0) + exp((double)a3 * 10.0);
  atomicAdd(&bden[j * B_ROWS + b], v);
}

// ---- kernel 5: GPS-filtered queue denominator (16 lanes per row, double exp-sum) ----
__global__ __launch_bounds__(256) void queue_kernel(const float* __restrict__ gps,
                                                    const float* __restrict__ sgps,
                                                    const float* __restrict__ sf,
                                                    const float* __restrict__ nn,
                                                    double* __restrict__ qden) {
  int b = blockIdx.x, tid = threadIdx.x;
  int w = tid >> 6, lane = tid & 63;
  __shared__ int qidx[QSZ];
  __shared__ int s_count;
  __shared__ int s_wcnt[4];
  __shared__ __align__(16) float s_nn[D_DIM];
  __shared__ double s_gsum[16];
  for (int k = tid; k < D_DIM; k += 256) s_nn[k] = nn[(size_t)b * D_DIM + k];
  if (tid == 0) s_count = 0;
  __syncthreads();

  const float r = 0.017453292519943295f;
  float lat1 = gps[b * 2 + 0] * r, lon1 = gps[b * 2 + 1] * r;
  float cl1 = cosf(lat1);
  int base = 0;
  while (true) {
    int count = s_count;
    if (count >= QSZ || base >= S_SUP) break;
    int s = base + tid;
    float lat2 = sgps[s * 2 + 0] * r, lon2 = sgps[s * 2 + 1] * r;
    float sdlat = sinf((lat2 - lat1) * 0.5f);
    float sdlon = sinf((lon2 - lon1) * 0.5f);
    float a = sdlat * sdlat + cl1 * cosf(lat2) * sdlon * sdlon;
    a = fminf(fmaxf(a, 0.f), 1.f);
    float d = 2.0f * 6371.0088f * asinf(sqrtf(a));
    bool valid = d > 25.0f;

    unsigned long long m = __ballot(valid);
    int wcnt = __popcll(m);
    if (lane == 0) s_wcnt[w] = wcnt;
    __syncthreads();
    int wbase = count;
    for (int i = 0; i < w; ++i) wbase += s_wcnt[i];
    int pos = wbase + __popcll(m & ((1ull << lane) - 1ull));
    if (valid && pos < QSZ) qidx[pos] = s;
    __syncthreads();
    if (tid == 0) {
      int total = s_wcnt[0] + s_wcnt[1] + s_wcnt[2] + s_wcnt[3];
      s_count = min(QSZ, count + total);
    }
    base += 256;
    __syncthreads();
  }
  int count = s_count;

  // phase 2: 16 lanes per row, 16 rows in flight per block
  int g  = lane >> 4;                  // group 0..3 within wave
  int l2 = lane & 15;
  double acc = 0.0;
  const float4* nn4 = (const float4*)s_nn;
  for (int q = w * 4 + g; q < count; q += 16) {
    const float4* row = (const float4*)(sf + (size_t)qidx[q] * D_DIM);
    float dot = 0.f;
    #pragma unroll
    for (int i = 0; i < 12; ++i) {
      float4 a = row[l2 + 16 * i];
      float4 nv = nn4[l2 + 16 * i];
      dot += a.x * nv.x + a.y * nv.y + a.z * nv.z + a.w * nv.w;
    }
    #pragma unroll
    for (int m2 = 8; m2 >= 1; m2 >>= 1) dot += __shfl_xor(dot, m2, 16);
    if (l2 == 0) acc += exp((double)dot * 10.0);
  }
  if (l2 == 0) s_gsum[w * 4 + g] = acc;
  __syncthreads();
  if (tid == 0) {
    double t = (double)(QSZ - count);
    #pragma unroll
    for (int i = 0; i < 16; ++i) t += s_gsum[i];
    qden[b] = t;
  }
}

// ---- kernel 6: final scalar loss (double) ----
__global__ __launch_bounds__(256) void loss_kernel(const float* __restrict__ num,
                                                   const double* __restrict__ bden,
                                                   const double* __restrict__ qden,
                                                   float* __restrict__ out) {
  int b = threadIdx.x;
  double q = qden[b];
  double n = (double)num[b];
  double t = 0.0;
  #pragma unroll
  for (int j = 0; j < 3; ++j) t += n - log(bden[j * B_ROWS + b] + q);
  t = block_sum_d(t);
  if (b == 0) out[0] = (float)(-t / 256.0);
}

extern "C" void kernel_launch(void* const* d_in, const int* in_sizes, int n_in,
                              void* d_out, int out_size, void* d_ws, size_t ws_size,
                              hipStream_t stream) {
  const float* V    = (const float*)d_in[0];   // (4,256,768)
  const float* L    = (const float*)d_in[1];   // (256,768)
  const float* gps  = (const float*)d_in[2];   // (256,2)
  const float* sf   = (const float*)d_in[3];   // (65536,768)
  const float* sgps = (const float*)d_in[4];   // (65536,2)
  float* out = (float*)d_out;

  char* ws = (char*)d_ws;
  size_t off = 0;
  unsigned short* orgb = (unsigned short*)(ws + off); off += 393216;  // 96 planes * 4 KB
  float* augs = (float*)(ws + off); off += 2359296;                   // 3*256*768*4
  float* nn   = (float*)(ws + off); off += 786432;
  float* nnT  = (float*)(ws + off); off += 786432;
  float* num  = (float*)(ws + off); off += 1024;                      // 256*4
  double* bden = (double*)(ws + off); off += 6144;                    // 3*256*8
  double* qden = (double*)(ws + off); off += 2048;                    // 256*8
  unsigned long long* gmax = (unsigned long long*)(ws + off); off += 2048;

  init_kernel<<<1, 256, 0, stream>>>(gmax, bden);
  prep_kernel<<<1024, 256, 0, stream>>>(V, L, orgb, augs);
  sim_argmax_kernel<<<S_SUP / 256, 512, 0, stream>>>(orgb, sf, gmax);
  nn_kernel<<<B_ROWS, 256, 0, stream>>>(gmax, sf, augs, nn, nnT, num);
  bden_kernel<<<192, 256, 0, stream>>>(augs, nnT, bden);
  queue_kernel<<<B_ROWS, 256, 0, stream>>>(gps, sgps, sf, nn, qden);
  loss_kernel<<<1, 256, 0, stream>>>(num, bden, qden, out);
}